// Round 1
// baseline (5936.563 us; speedup 1.0000x reference)
//
#include <hip/hip_runtime.h>

#define D 128
#define NLAYERS 5

// ---------------- gather: h = emb[x], dual-store into H and G ----------------
__global__ void gather_kernel(const int* __restrict__ x, const float* __restrict__ emb,
                              float* __restrict__ h, float* __restrict__ g, int n_nodes) {
    int tid = blockIdx.x * 256 + threadIdx.x;
    int node = tid >> 5;                 // 32 threads per node (128 dims / float4)
    if (node >= n_nodes) return;
    int d4 = (tid & 31) << 2;
    int s = x[node];
    const float4 v = *reinterpret_cast<const float4*>(emb + (size_t)s * D + d4);
    *reinterpret_cast<float4*>(h + (size_t)node * D + d4) = v;
    *reinterpret_cast<float4*>(g + (size_t)node * D + d4) = v;
}

// ---------------- scatter-add: g[dst] += h[src] over edges ----------------
__global__ void scatter_kernel(const int* __restrict__ esrc, const int* __restrict__ edst,
                               const float* __restrict__ h, float* __restrict__ g, int n_edges) {
    int tid = blockIdx.x * 256 + threadIdx.x;
    int e = tid >> 5;                    // 32 threads per edge
    if (e >= n_edges) return;
    int d4 = (tid & 31) << 2;
    int s = esrc[e], t = edst[e];
    const float4 v = *reinterpret_cast<const float4*>(h + (size_t)s * D + d4);
    float* p = g + (size_t)t * D + d4;
    atomicAdd(p + 0, v.x);
    atomicAdd(p + 1, v.y);
    atomicAdd(p + 2, v.z);
    atomicAdd(p + 3, v.w);
}

// ---------------- fused GEMM + bias + ReLU ----------------
// out[r][col0+c] = relu(sum_k in[r][k] * W[k][col0+c] + bias[col0+c])
// 64x64 tile per block; 16x16 threads, 4x4 micro-tile per thread.
// LDS = 32KB W-slice + 32KB z-tile = exactly 64KB -> 2 blocks/CU.
__global__ __launch_bounds__(256) void gemm_relu_kernel(
        const float* __restrict__ in, const float* __restrict__ W,
        const float* __restrict__ bias, float* __restrict__ out,
        float* __restrict__ out2, int n_rows) {
    __shared__ float ws[D][64];   // W[k][col0 + c]
    __shared__ float zs[64][D];   // in[row0 + r][k]

    const int tid  = threadIdx.x;
    const int row0 = blockIdx.x * 64;
    const int col0 = blockIdx.y * 64;

    // stage W slice: 128x64 floats = 2048 float4
    #pragma unroll
    for (int i = 0; i < 8; i++) {
        int idx = i * 256 + tid;
        int k  = idx >> 4;
        int c4 = (idx & 15) << 2;
        *reinterpret_cast<float4*>(&ws[k][c4]) =
            *reinterpret_cast<const float4*>(W + (size_t)k * D + col0 + c4);
    }
    // stage z tile: 64x128 floats = 2048 float4
    #pragma unroll
    for (int i = 0; i < 8; i++) {
        int idx = i * 256 + tid;
        int r  = idx >> 5;
        int c4 = (idx & 31) << 2;
        int gr = row0 + r;
        float4 v = make_float4(0.f, 0.f, 0.f, 0.f);
        if (gr < n_rows) v = *reinterpret_cast<const float4*>(in + (size_t)gr * D + c4);
        *reinterpret_cast<float4*>(&zs[r][c4]) = v;
    }
    __syncthreads();

    const int tx = tid & 15, ty = tid >> 4;
    float acc[4][4];
    #pragma unroll
    for (int i = 0; i < 4; i++)
        #pragma unroll
        for (int j = 0; j < 4; j++) acc[i][j] = 0.f;

    #pragma unroll 4
    for (int k = 0; k < D; k++) {
        float4 b = *reinterpret_cast<const float4*>(&ws[k][tx * 4]);
        float a0 = zs[ty * 4 + 0][k];
        float a1 = zs[ty * 4 + 1][k];
        float a2 = zs[ty * 4 + 2][k];
        float a3 = zs[ty * 4 + 3][k];
        acc[0][0] += a0 * b.x; acc[0][1] += a0 * b.y; acc[0][2] += a0 * b.z; acc[0][3] += a0 * b.w;
        acc[1][0] += a1 * b.x; acc[1][1] += a1 * b.y; acc[1][2] += a1 * b.z; acc[1][3] += a1 * b.w;
        acc[2][0] += a2 * b.x; acc[2][1] += a2 * b.y; acc[2][2] += a2 * b.z; acc[2][3] += a2 * b.w;
        acc[3][0] += a3 * b.x; acc[3][1] += a3 * b.y; acc[3][2] += a3 * b.z; acc[3][3] += a3 * b.w;
    }

    const float4 bv = *reinterpret_cast<const float4*>(bias + col0 + tx * 4);
    #pragma unroll
    for (int i = 0; i < 4; i++) {
        int r = row0 + ty * 4 + i;
        if (r >= n_rows) continue;
        float4 o;
        o.x = fmaxf(acc[i][0] + bv.x, 0.f);
        o.y = fmaxf(acc[i][1] + bv.y, 0.f);
        o.z = fmaxf(acc[i][2] + bv.z, 0.f);
        o.w = fmaxf(acc[i][3] + bv.w, 0.f);
        *reinterpret_cast<float4*>(out + (size_t)r * D + col0 + tx * 4) = o;
        if (out2 != nullptr)
            *reinterpret_cast<float4*>(out2 + (size_t)r * D + col0 + tx * 4) = o;
    }
}

// ---------------- pooling ----------------
__global__ void zero_kernel(float* __restrict__ p) { p[threadIdx.x] = 0.f; }

__global__ void pool_kernel(const float* __restrict__ h, float* __restrict__ pooled, int n_rows) {
    const int c  = threadIdx.x & 127;
    const int rp = threadIdx.x >> 7;     // 0 or 1
    const int r0 = blockIdx.x * 512;
    const int rend = min(r0 + 512, n_rows);
    float s = 0.f;
    for (int r = r0 + rp; r < rend; r += 2)
        s += h[(size_t)r * D + c];
    __shared__ float red[128];
    if (rp == 1) red[c] = s;
    __syncthreads();
    if (rp == 0) atomicAdd(&pooled[c], s + red[c]);
}

// ---------------- final linear: out = pooled @ Wlin + blin ----------------
__global__ void final_kernel(const float* __restrict__ pooled, const float* __restrict__ Wlin,
                             const float* __restrict__ blin, float* __restrict__ out) {
    const int j = threadIdx.x;           // 128 threads
    __shared__ float p[D];
    p[j] = pooled[j];
    __syncthreads();
    float s = blin[j];
    #pragma unroll 8
    for (int k = 0; k < D; k++) s += p[k] * Wlin[k * D + j];
    out[j] = s;
}

extern "C" void kernel_launch(void* const* d_in, const int* in_sizes, int n_in,
                              void* d_out, int out_size, void* d_ws, size_t ws_size,
                              hipStream_t stream) {
    const int*   x    = (const int*)d_in[0];
    const int*   ei   = (const int*)d_in[1];
    const float* emb  = (const float*)d_in[2];
    const float* Wa   = (const float*)d_in[3];
    const float* ba   = (const float*)d_in[4];
    const float* Wb   = (const float*)d_in[5];
    const float* bb   = (const float*)d_in[6];
    const float* Wlin = (const float*)d_in[7];
    const float* blin = (const float*)d_in[8];
    float* out = (float*)d_out;

    const int N = in_sizes[0];
    const int E = in_sizes[1] / 2;
    const int* esrc = ei;
    const int* edst = ei + E;

    // workspace layout: H | G | T | pooled   (3 * N * D * 4B + 512B)
    float* H = (float*)d_ws;
    float* G = H + (size_t)N * D;
    float* T = G + (size_t)N * D;
    float* pooled = T + (size_t)N * D;

    dim3 gemm_grid((N + 63) / 64, 2);

    gather_kernel<<<(N * 32 + 255) / 256, 256, 0, stream>>>(x, emb, H, G, N);

    for (int l = 0; l < NLAYERS; l++) {
        scatter_kernel<<<(E * 32 + 255) / 256, 256, 0, stream>>>(esrc, edst, H, G, E);
        gemm_relu_kernel<<<gemm_grid, 256, 0, stream>>>(
            G, Wa + (size_t)l * D * D, ba + (size_t)l * D, T, nullptr, N);
        gemm_relu_kernel<<<gemm_grid, 256, 0, stream>>>(
            T, Wb + (size_t)l * D * D, bb + (size_t)l * D, G, H, N);
    }

    zero_kernel<<<1, 128, 0, stream>>>(pooled);
    pool_kernel<<<(N + 511) / 512, 256, 0, stream>>>(H, pooled, N);
    final_kernel<<<1, 128, 0, stream>>>(pooled, Wlin, blin, out);
}

// Round 2
// 1175.991 us; speedup vs baseline: 5.0481x; 5.0481x over previous
//
#include <hip/hip_runtime.h>

#define D 128
#define NLAYERS 5
#define SCAN_TILE 1024   // elements per scan block (256 threads x 4)

// ---------------- gather: h = emb[x] ----------------
__global__ void gather_kernel(const int* __restrict__ x, const float* __restrict__ emb,
                              float* __restrict__ h, int n_nodes) {
    int tid = blockIdx.x * 256 + threadIdx.x;
    int node = tid >> 5;                 // 32 threads per node (128 dims / float4)
    if (node >= n_nodes) return;
    int d4 = (tid & 31) << 2;
    int s = x[node];
    const float4 v = *reinterpret_cast<const float4*>(emb + (size_t)s * D + d4);
    *reinterpret_cast<float4*>(h + (size_t)node * D + d4) = v;
}

// ---------------- CSR build ----------------
__global__ void zero_int_kernel(int* __restrict__ p, int n) {
    int i = blockIdx.x * 256 + threadIdx.x;
    if (i < n) p[i] = 0;
}

__global__ void hist_kernel(const int* __restrict__ edst, int* __restrict__ deg, int n_edges) {
    int e = blockIdx.x * 256 + threadIdx.x;
    if (e < n_edges) atomicAdd(&deg[edst[e]], 1);
}

// per-block sums of deg (SCAN_TILE elems / block)
__global__ void scan_sums_kernel(const int* __restrict__ deg, int* __restrict__ bsums, int n) {
    __shared__ int red[256];
    int base = blockIdx.x * SCAN_TILE + threadIdx.x * 4;
    int s = 0;
    #pragma unroll
    for (int j = 0; j < 4; j++) {
        int i = base + j;
        if (i < n) s += deg[i];
    }
    red[threadIdx.x] = s;
    __syncthreads();
    for (int off = 128; off > 0; off >>= 1) {
        if (threadIdx.x < off) red[threadIdx.x] += red[threadIdx.x + off];
        __syncthreads();
    }
    if (threadIdx.x == 0) bsums[blockIdx.x] = red[0];
}

// single-block exclusive scan of block sums (handles any nblocks via carry loop)
__global__ void scan_bsums_kernel(int* __restrict__ bsums, int nblocks) {
    __shared__ int sdata[256];
    int carry = 0;
    for (int base = 0; base < nblocks; base += 256) {
        int i = base + threadIdx.x;
        int v = (i < nblocks) ? bsums[i] : 0;
        sdata[threadIdx.x] = v;
        __syncthreads();
        for (int off = 1; off < 256; off <<= 1) {
            int t = (threadIdx.x >= off) ? sdata[threadIdx.x - off] : 0;
            __syncthreads();
            sdata[threadIdx.x] += t;
            __syncthreads();
        }
        int incl = sdata[threadIdx.x];
        if (i < nblocks) bsums[i] = carry + incl - v;   // exclusive
        carry += sdata[255];
        __syncthreads();
    }
}

// final scan: offsets[i] = exclusive prefix of deg for i in [0, n]; cursor copy for i < n
__global__ void scan_final_kernel(const int* __restrict__ deg, const int* __restrict__ bsums,
                                  int* __restrict__ offsets, int* __restrict__ cursor, int n) {
    __shared__ int sdata[256];
    int base = blockIdx.x * SCAN_TILE + threadIdx.x * 4;
    int v[4];
    int s = 0;
    #pragma unroll
    for (int j = 0; j < 4; j++) {
        int i = base + j;
        v[j] = (i < n) ? deg[i] : 0;
        s += v[j];
    }
    sdata[threadIdx.x] = s;
    __syncthreads();
    for (int off = 1; off < 256; off <<= 1) {
        int t = (threadIdx.x >= off) ? sdata[threadIdx.x - off] : 0;
        __syncthreads();
        sdata[threadIdx.x] += t;
        __syncthreads();
    }
    int excl = sdata[threadIdx.x] - s + bsums[blockIdx.x];
    #pragma unroll
    for (int j = 0; j < 4; j++) {
        int i = base + j;
        if (i <= n) offsets[i] = excl;
        if (i < n) cursor[i] = excl;
        excl += v[j];
    }
}

__global__ void fill_kernel(const int* __restrict__ esrc, const int* __restrict__ edst,
                            int* __restrict__ cursor, int* __restrict__ csr_src, int n_edges) {
    int e = blockIdx.x * 256 + threadIdx.x;
    if (e >= n_edges) return;
    int pos = atomicAdd(&cursor[edst[e]], 1);
    csr_src[pos] = esrc[e];
}

// ---------------- aggregation: g[i] = h[i] + sum_{j->i} h[j]  (no atomics) ----------------
__global__ void aggregate_kernel(const int* __restrict__ offsets, const int* __restrict__ csr_src,
                                 const float* __restrict__ h, float* __restrict__ g, int n_nodes) {
    int tid = blockIdx.x * 256 + threadIdx.x;
    int node = tid >> 5;                 // 32 lanes per node
    if (node >= n_nodes) return;
    int d4 = (tid & 31) << 2;
    float4 acc = *reinterpret_cast<const float4*>(h + (size_t)node * D + d4);  // self term
    int beg = offsets[node];
    int end = offsets[node + 1];
    int e = beg;
    // 2-way unrolled for memory-level parallelism
    for (; e + 1 < end; e += 2) {
        int s0 = csr_src[e];
        int s1 = csr_src[e + 1];
        float4 v0 = *reinterpret_cast<const float4*>(h + (size_t)s0 * D + d4);
        float4 v1 = *reinterpret_cast<const float4*>(h + (size_t)s1 * D + d4);
        acc.x += v0.x + v1.x; acc.y += v0.y + v1.y;
        acc.z += v0.z + v1.z; acc.w += v0.w + v1.w;
    }
    if (e < end) {
        int s0 = csr_src[e];
        float4 v0 = *reinterpret_cast<const float4*>(h + (size_t)s0 * D + d4);
        acc.x += v0.x; acc.y += v0.y; acc.z += v0.z; acc.w += v0.w;
    }
    *reinterpret_cast<float4*>(g + (size_t)node * D + d4) = acc;
}

// ---------------- fused GEMM + bias + ReLU ----------------
__global__ __launch_bounds__(256) void gemm_relu_kernel(
        const float* __restrict__ in, const float* __restrict__ W,
        const float* __restrict__ bias, float* __restrict__ out,
        float* __restrict__ out2, int n_rows) {
    __shared__ float ws[D][64];   // W[k][col0 + c]
    __shared__ float zs[64][D];   // in[row0 + r][k]

    const int tid  = threadIdx.x;
    const int row0 = blockIdx.x * 64;
    const int col0 = blockIdx.y * 64;

    #pragma unroll
    for (int i = 0; i < 8; i++) {
        int idx = i * 256 + tid;
        int k  = idx >> 4;
        int c4 = (idx & 15) << 2;
        *reinterpret_cast<float4*>(&ws[k][c4]) =
            *reinterpret_cast<const float4*>(W + (size_t)k * D + col0 + c4);
    }
    #pragma unroll
    for (int i = 0; i < 8; i++) {
        int idx = i * 256 + tid;
        int r  = idx >> 5;
        int c4 = (idx & 31) << 2;
        int gr = row0 + r;
        float4 v = make_float4(0.f, 0.f, 0.f, 0.f);
        if (gr < n_rows) v = *reinterpret_cast<const float4*>(in + (size_t)gr * D + c4);
        *reinterpret_cast<float4*>(&zs[r][c4]) = v;
    }
    __syncthreads();

    const int tx = tid & 15, ty = tid >> 4;
    float acc[4][4];
    #pragma unroll
    for (int i = 0; i < 4; i++)
        #pragma unroll
        for (int j = 0; j < 4; j++) acc[i][j] = 0.f;

    #pragma unroll 4
    for (int k = 0; k < D; k++) {
        float4 b = *reinterpret_cast<const float4*>(&ws[k][tx * 4]);
        float a0 = zs[ty * 4 + 0][k];
        float a1 = zs[ty * 4 + 1][k];
        float a2 = zs[ty * 4 + 2][k];
        float a3 = zs[ty * 4 + 3][k];
        acc[0][0] += a0 * b.x; acc[0][1] += a0 * b.y; acc[0][2] += a0 * b.z; acc[0][3] += a0 * b.w;
        acc[1][0] += a1 * b.x; acc[1][1] += a1 * b.y; acc[1][2] += a1 * b.z; acc[1][3] += a1 * b.w;
        acc[2][0] += a2 * b.x; acc[2][1] += a2 * b.y; acc[2][2] += a2 * b.z; acc[2][3] += a2 * b.w;
        acc[3][0] += a3 * b.x; acc[3][1] += a3 * b.y; acc[3][2] += a3 * b.z; acc[3][3] += a3 * b.w;
    }

    const float4 bv = *reinterpret_cast<const float4*>(bias + col0 + tx * 4);
    #pragma unroll
    for (int i = 0; i < 4; i++) {
        int r = row0 + ty * 4 + i;
        if (r >= n_rows) continue;
        float4 o;
        o.x = fmaxf(acc[i][0] + bv.x, 0.f);
        o.y = fmaxf(acc[i][1] + bv.y, 0.f);
        o.z = fmaxf(acc[i][2] + bv.z, 0.f);
        o.w = fmaxf(acc[i][3] + bv.w, 0.f);
        *reinterpret_cast<float4*>(out + (size_t)r * D + col0 + tx * 4) = o;
        if (out2 != nullptr)
            *reinterpret_cast<float4*>(out2 + (size_t)r * D + col0 + tx * 4) = o;
    }
}

// ---------------- pooling ----------------
__global__ void zero_kernel(float* __restrict__ p) { p[threadIdx.x] = 0.f; }

__global__ void pool_kernel(const float* __restrict__ h, float* __restrict__ pooled, int n_rows) {
    const int c  = threadIdx.x & 127;
    const int rp = threadIdx.x >> 7;     // 0 or 1
    const int r0 = blockIdx.x * 512;
    const int rend = min(r0 + 512, n_rows);
    float s = 0.f;
    for (int r = r0 + rp; r < rend; r += 2)
        s += h[(size_t)r * D + c];
    __shared__ float red[128];
    if (rp == 1) red[c] = s;
    __syncthreads();
    if (rp == 0) atomicAdd(&pooled[c], s + red[c]);
}

// ---------------- final linear ----------------
__global__ void final_kernel(const float* __restrict__ pooled, const float* __restrict__ Wlin,
                             const float* __restrict__ blin, float* __restrict__ out) {
    const int j = threadIdx.x;           // 128 threads
    __shared__ float p[D];
    p[j] = pooled[j];
    __syncthreads();
    float s = blin[j];
    #pragma unroll 8
    for (int k = 0; k < D; k++) s += p[k] * Wlin[k * D + j];
    out[j] = s;
}

extern "C" void kernel_launch(void* const* d_in, const int* in_sizes, int n_in,
                              void* d_out, int out_size, void* d_ws, size_t ws_size,
                              hipStream_t stream) {
    const int*   x    = (const int*)d_in[0];
    const int*   ei   = (const int*)d_in[1];
    const float* emb  = (const float*)d_in[2];
    const float* Wa   = (const float*)d_in[3];
    const float* ba   = (const float*)d_in[4];
    const float* Wb   = (const float*)d_in[5];
    const float* bb   = (const float*)d_in[6];
    const float* Wlin = (const float*)d_in[7];
    const float* blin = (const float*)d_in[8];
    float* out = (float*)d_out;

    const int N = in_sizes[0];
    const int E = in_sizes[1] / 2;
    const int* esrc = ei;
    const int* edst = ei + E;

    // workspace layout
    float* H = (float*)d_ws;
    float* G = H + (size_t)N * D;
    float* T = G + (size_t)N * D;
    float* pooled = T + (size_t)N * D;
    int* deg     = (int*)(pooled + 128);      // N
    int* offsets = deg + N;                   // N+1
    int* cursor  = offsets + (N + 1);         // N
    int* bsums   = cursor + N;                // nblocks (pad to 4096)
    int* csr_src = bsums + 4096;              // E

    const int scan_blocks = (N + 1 + SCAN_TILE - 1) / SCAN_TILE;

    // --- CSR build ---
    zero_int_kernel<<<(N + 255) / 256, 256, 0, stream>>>(deg, N);
    hist_kernel<<<(E + 255) / 256, 256, 0, stream>>>(edst, deg, E);
    scan_sums_kernel<<<scan_blocks, 256, 0, stream>>>(deg, bsums, N);
    scan_bsums_kernel<<<1, 256, 0, stream>>>(bsums, scan_blocks);
    scan_final_kernel<<<scan_blocks, 256, 0, stream>>>(deg, bsums, offsets, cursor, N);
    fill_kernel<<<(E + 255) / 256, 256, 0, stream>>>(esrc, edst, cursor, csr_src, E);

    // --- h = emb[x] ---
    gather_kernel<<<(N * 32 + 255) / 256, 256, 0, stream>>>(x, emb, H, N);

    dim3 gemm_grid((N + 63) / 64, 2);
    for (int l = 0; l < NLAYERS; l++) {
        aggregate_kernel<<<((size_t)N * 32 + 255) / 256, 256, 0, stream>>>(offsets, csr_src, H, G, N);
        gemm_relu_kernel<<<gemm_grid, 256, 0, stream>>>(
            G, Wa + (size_t)l * D * D, ba + (size_t)l * D, T, nullptr, N);
        gemm_relu_kernel<<<gemm_grid, 256, 0, stream>>>(
            T, Wb + (size_t)l * D * D, bb + (size_t)l * D, G, H, N);
    }

    zero_kernel<<<1, 128, 0, stream>>>(pooled);
    pool_kernel<<<(N + 511) / 512, 256, 0, stream>>>(H, pooled, N);
    final_kernel<<<1, 128, 0, stream>>>(pooled, Wlin, blin, out);
}

// Round 3
// 888.399 us; speedup vs baseline: 6.6823x; 1.3237x over previous
//
#include <hip/hip_runtime.h>

#define D 128
#define NLAYERS 5
#define SCAN_TILE 1024

using short8  = __attribute__((ext_vector_type(8))) short;
using floatx4 = __attribute__((ext_vector_type(4))) float;

// round-to-nearest-even fp32 -> bf16 (returns upper-16 bit pattern)
__device__ __forceinline__ unsigned bf16_rne(float x) {
    unsigned u = __float_as_uint(x);
    return (u + 0x7fffu + ((u >> 16) & 1u)) >> 16;
}

// ---------------- gather: h = emb[x] ----------------
__global__ void gather_kernel(const int* __restrict__ x, const float* __restrict__ emb,
                              float* __restrict__ h, int n_nodes) {
    int tid = blockIdx.x * 256 + threadIdx.x;
    int node = tid >> 5;
    if (node >= n_nodes) return;
    int d4 = (tid & 31) << 2;
    int s = x[node];
    const float4 v = *reinterpret_cast<const float4*>(emb + (size_t)s * D + d4);
    *reinterpret_cast<float4*>(h + (size_t)node * D + d4) = v;
}

// ---------------- CSR build ----------------
__global__ void zero_int_kernel(int* __restrict__ p, int n) {
    int i = blockIdx.x * 256 + threadIdx.x;
    if (i < n) p[i] = 0;
}

__global__ void hist_kernel(const int* __restrict__ edst, int* __restrict__ deg, int n_edges) {
    int e = blockIdx.x * 256 + threadIdx.x;
    if (e < n_edges) atomicAdd(&deg[edst[e]], 1);
}

__global__ void scan_sums_kernel(const int* __restrict__ deg, int* __restrict__ bsums, int n) {
    __shared__ int red[256];
    int base = blockIdx.x * SCAN_TILE + threadIdx.x * 4;
    int s = 0;
    #pragma unroll
    for (int j = 0; j < 4; j++) {
        int i = base + j;
        if (i < n) s += deg[i];
    }
    red[threadIdx.x] = s;
    __syncthreads();
    for (int off = 128; off > 0; off >>= 1) {
        if (threadIdx.x < off) red[threadIdx.x] += red[threadIdx.x + off];
        __syncthreads();
    }
    if (threadIdx.x == 0) bsums[blockIdx.x] = red[0];
}

__global__ void scan_bsums_kernel(int* __restrict__ bsums, int nblocks) {
    __shared__ int sdata[256];
    int carry = 0;
    for (int base = 0; base < nblocks; base += 256) {
        int i = base + threadIdx.x;
        int v = (i < nblocks) ? bsums[i] : 0;
        sdata[threadIdx.x] = v;
        __syncthreads();
        for (int off = 1; off < 256; off <<= 1) {
            int t = (threadIdx.x >= off) ? sdata[threadIdx.x - off] : 0;
            __syncthreads();
            sdata[threadIdx.x] += t;
            __syncthreads();
        }
        int incl = sdata[threadIdx.x];
        if (i < nblocks) bsums[i] = carry + incl - v;
        carry += sdata[255];
        __syncthreads();
    }
}

__global__ void scan_final_kernel(const int* __restrict__ deg, const int* __restrict__ bsums,
                                  int* __restrict__ offsets, int* __restrict__ cursor, int n) {
    __shared__ int sdata[256];
    int base = blockIdx.x * SCAN_TILE + threadIdx.x * 4;
    int v[4];
    int s = 0;
    #pragma unroll
    for (int j = 0; j < 4; j++) {
        int i = base + j;
        v[j] = (i < n) ? deg[i] : 0;
        s += v[j];
    }
    sdata[threadIdx.x] = s;
    __syncthreads();
    for (int off = 1; off < 256; off <<= 1) {
        int t = (threadIdx.x >= off) ? sdata[threadIdx.x - off] : 0;
        __syncthreads();
        sdata[threadIdx.x] += t;
        __syncthreads();
    }
    int excl = sdata[threadIdx.x] - s + bsums[blockIdx.x];
    #pragma unroll
    for (int j = 0; j < 4; j++) {
        int i = base + j;
        if (i <= n) offsets[i] = excl;
        if (i < n) cursor[i] = excl;
        excl += v[j];
    }
}

__global__ void fill_kernel(const int* __restrict__ esrc, const int* __restrict__ edst,
                            int* __restrict__ cursor, int* __restrict__ csr_src, int n_edges) {
    int e = blockIdx.x * 256 + threadIdx.x;
    if (e >= n_edges) return;
    int pos = atomicAdd(&cursor[edst[e]], 1);
    csr_src[pos] = esrc[e];
}

// ---------------- aggregation: g[i] = h[i] + sum_{j->i} h[j] ----------------
__global__ void aggregate_kernel(const int* __restrict__ offsets, const int* __restrict__ csr_src,
                                 const float* __restrict__ h, float* __restrict__ g, int n_nodes) {
    int tid = blockIdx.x * 256 + threadIdx.x;
    int node = tid >> 5;
    if (node >= n_nodes) return;
    int d4 = (tid & 31) << 2;
    float4 acc = *reinterpret_cast<const float4*>(h + (size_t)node * D + d4);
    int beg = offsets[node];
    int end = offsets[node + 1];
    int e = beg;
    for (; e + 1 < end; e += 2) {
        int s0 = csr_src[e];
        int s1 = csr_src[e + 1];
        float4 v0 = *reinterpret_cast<const float4*>(h + (size_t)s0 * D + d4);
        float4 v1 = *reinterpret_cast<const float4*>(h + (size_t)s1 * D + d4);
        acc.x += v0.x + v1.x; acc.y += v0.y + v1.y;
        acc.z += v0.z + v1.z; acc.w += v0.w + v1.w;
    }
    if (e < end) {
        int s0 = csr_src[e];
        float4 v0 = *reinterpret_cast<const float4*>(h + (size_t)s0 * D + d4);
        acc.x += v0.x; acc.y += v0.y; acc.z += v0.z; acc.w += v0.w;
    }
    *reinterpret_cast<float4*>(g + (size_t)node * D + d4) = acc;
}

// ---------------- W pre-split: wt[mat][n][k] = bf16(W[mat][k][n]) ----------------
__global__ void wsplit_kernel(const float* __restrict__ Wa, const float* __restrict__ Wb,
                              short* __restrict__ wt) {
    int mat = blockIdx.y;   // 2l -> Wa[l], 2l+1 -> Wb[l]
    const float* W = (mat & 1) ? (Wb + (size_t)(mat >> 1) * D * D)
                               : (Wa + (size_t)(mat >> 1) * D * D);
    int idx = blockIdx.x * 256 + threadIdx.x;   // over [n][k], 16384
    int n = idx >> 7, k = idx & 127;
    wt[(size_t)mat * D * D + idx] = (short)bf16_rne(W[k * D + n]);
}

// ---------------- MFMA GEMM: out = relu(in @ W + bias), split-bf16 ----------------
// block: 64 rows x 128 cols, 4 waves of 32x64. K=128 fully staged.
// LDS: zhi/zlo 16KB each + wsh 32KB = 64KB -> 2 blocks/CU.
// 16B chunks XOR-swizzled: chunk c of row r stored at (c ^ (r&15)).
__global__ __launch_bounds__(256) void gemm_mfma_kernel(
        const float* __restrict__ in, const short* __restrict__ wt,
        const float* __restrict__ bias, float* __restrict__ out,
        float* __restrict__ out2, int n_rows) {
    __shared__ __align__(16) short zhi[64 * 128];
    __shared__ __align__(16) short zlo[64 * 128];
    __shared__ __align__(16) short wsh[128 * 128];

    const int tid  = threadIdx.x;
    const int row0 = blockIdx.x * 64;

    // stage W (bf16, [n][k]): 2048 chunks of 8 shorts
    #pragma unroll
    for (int i = 0; i < 8; i++) {
        int g = i * 256 + tid;
        int n = g >> 4, c = g & 15;
        short8 v = *reinterpret_cast<const short8*>(wt + n * D + c * 8);
        *reinterpret_cast<short8*>(&wsh[(n * 16 + (c ^ (n & 15))) * 8]) = v;
    }
    // stage z (fp32 -> hi/lo bf16): 1024 chunks
    #pragma unroll
    for (int i = 0; i < 4; i++) {
        int g = i * 256 + tid;
        int r = g >> 4, c = g & 15;
        int gr = row0 + r;
        float f[8];
        if (gr < n_rows) {
            float4 v0 = *reinterpret_cast<const float4*>(in + (size_t)gr * D + c * 8);
            float4 v1 = *reinterpret_cast<const float4*>(in + (size_t)gr * D + c * 8 + 4);
            f[0]=v0.x; f[1]=v0.y; f[2]=v0.z; f[3]=v0.w;
            f[4]=v1.x; f[5]=v1.y; f[6]=v1.z; f[7]=v1.w;
        } else {
            #pragma unroll
            for (int j = 0; j < 8; j++) f[j] = 0.f;
        }
        short8 hi, lo;
        #pragma unroll
        for (int j = 0; j < 8; j++) {
            unsigned h = bf16_rne(f[j]);
            hi[j] = (short)h;
            lo[j] = (short)bf16_rne(f[j] - __uint_as_float(h << 16));
        }
        int off = (r * 16 + (c ^ (r & 15))) * 8;
        *reinterpret_cast<short8*>(&zhi[off]) = hi;
        *reinterpret_cast<short8*>(&zlo[off]) = lo;
    }
    __syncthreads();

    const int lane = tid & 63;
    const int wave = tid >> 6;
    const int wr   = wave >> 1;     // row group (32 rows)
    const int wc   = wave & 1;      // col group (64 cols)
    const int lm   = lane & 15;
    const int quad = lane >> 4;

    floatx4 acc[2][4];
    #pragma unroll
    for (int a = 0; a < 2; a++)
        #pragma unroll
        for (int b = 0; b < 4; b++) acc[a][b] = floatx4{0.f, 0.f, 0.f, 0.f};

    #pragma unroll
    for (int ks = 0; ks < 4; ks++) {
        short8 ah[2], al[2], bh[4];
        const int c = ks * 4 + quad;
        #pragma unroll
        for (int rs = 0; rs < 2; rs++) {
            int r = wr * 32 + rs * 16 + lm;
            int off = (r * 16 + (c ^ (r & 15))) * 8;
            ah[rs] = *reinterpret_cast<const short8*>(&zhi[off]);
            al[rs] = *reinterpret_cast<const short8*>(&zlo[off]);
        }
        #pragma unroll
        for (int cs = 0; cs < 4; cs++) {
            int n = wc * 64 + cs * 16 + lm;
            bh[cs] = *reinterpret_cast<const short8*>(&wsh[(n * 16 + (c ^ (n & 15))) * 8]);
        }
        #pragma unroll
        for (int rs = 0; rs < 2; rs++)
            #pragma unroll
            for (int cs = 0; cs < 4; cs++) {
                acc[rs][cs] = __builtin_amdgcn_mfma_f32_16x16x32_bf16(ah[rs], bh[cs], acc[rs][cs], 0, 0, 0);
                acc[rs][cs] = __builtin_amdgcn_mfma_f32_16x16x32_bf16(al[rs], bh[cs], acc[rs][cs], 0, 0, 0);
            }
    }

    // epilogue: bias + relu + store (C layout: row = quad*4+reg, col = lm)
    #pragma unroll
    for (int cs = 0; cs < 4; cs++) {
        int col = wc * 64 + cs * 16 + lm;
        float bv = bias[col];
        #pragma unroll
        for (int rs = 0; rs < 2; rs++) {
            #pragma unroll
            for (int reg = 0; reg < 4; reg++) {
                int r = row0 + wr * 32 + rs * 16 + quad * 4 + reg;
                if (r < n_rows) {
                    float v = fmaxf(acc[rs][cs][reg] + bv, 0.f);
                    out[(size_t)r * D + col] = v;
                    if (out2 != nullptr) out2[(size_t)r * D + col] = v;
                }
            }
        }
    }
}

// ---------------- pooling ----------------
__global__ void zero_kernel(float* __restrict__ p) { p[threadIdx.x] = 0.f; }

__global__ void pool_kernel(const float* __restrict__ h, float* __restrict__ pooled, int n_rows) {
    const int c  = threadIdx.x & 127;
    const int rp = threadIdx.x >> 7;
    const int r0 = blockIdx.x * 512;
    const int rend = min(r0 + 512, n_rows);
    float s = 0.f;
    for (int r = r0 + rp; r < rend; r += 2)
        s += h[(size_t)r * D + c];
    __shared__ float red[128];
    if (rp == 1) red[c] = s;
    __syncthreads();
    if (rp == 0) atomicAdd(&pooled[c], s + red[c]);
}

// ---------------- final linear ----------------
__global__ void final_kernel(const float* __restrict__ pooled, const float* __restrict__ Wlin,
                             const float* __restrict__ blin, float* __restrict__ out) {
    const int j = threadIdx.x;
    __shared__ float p[D];
    p[j] = pooled[j];
    __syncthreads();
    float s = blin[j];
    #pragma unroll 8
    for (int k = 0; k < D; k++) s += p[k] * Wlin[k * D + j];
    out[j] = s;
}

extern "C" void kernel_launch(void* const* d_in, const int* in_sizes, int n_in,
                              void* d_out, int out_size, void* d_ws, size_t ws_size,
                              hipStream_t stream) {
    const int*   x    = (const int*)d_in[0];
    const int*   ei   = (const int*)d_in[1];
    const float* emb  = (const float*)d_in[2];
    const float* Wa   = (const float*)d_in[3];
    const float* ba   = (const float*)d_in[4];
    const float* Wb   = (const float*)d_in[5];
    const float* bb   = (const float*)d_in[6];
    const float* Wlin = (const float*)d_in[7];
    const float* blin = (const float*)d_in[8];
    float* out = (float*)d_out;

    const int N = in_sizes[0];
    const int E = in_sizes[1] / 2;
    const int* esrc = ei;
    const int* edst = ei + E;

    // workspace layout
    float* H = (float*)d_ws;
    float* G = H + (size_t)N * D;
    float* T = G + (size_t)N * D;
    float* pooled = T + (size_t)N * D;
    int* deg     = (int*)(pooled + 128);
    int* offsets = deg + N;
    int* cursor  = offsets + (N + 1);
    int* bsums   = cursor + N;
    int* csr_src = bsums + 4096;
    uintptr_t wt_addr = ((uintptr_t)(csr_src + E) + 15) & ~(uintptr_t)15;
    short* wt = (short*)wt_addr;     // [10][128][128] bf16

    const int scan_blocks = (N + 1 + SCAN_TILE - 1) / SCAN_TILE;

    // --- W pre-split (once per launch) ---
    wsplit_kernel<<<dim3(64, 2 * NLAYERS), 256, 0, stream>>>(Wa, Wb, wt);

    // --- CSR build ---
    zero_int_kernel<<<(N + 255) / 256, 256, 0, stream>>>(deg, N);
    hist_kernel<<<(E + 255) / 256, 256, 0, stream>>>(edst, deg, E);
    scan_sums_kernel<<<scan_blocks, 256, 0, stream>>>(deg, bsums, N);
    scan_bsums_kernel<<<1, 256, 0, stream>>>(bsums, scan_blocks);
    scan_final_kernel<<<scan_blocks, 256, 0, stream>>>(deg, bsums, offsets, cursor, N);
    fill_kernel<<<(E + 255) / 256, 256, 0, stream>>>(esrc, edst, cursor, csr_src, E);

    // --- h = emb[x] ---
    gather_kernel<<<(N * 32 + 255) / 256, 256, 0, stream>>>(x, emb, H, N);

    const int gemm_blocks = (N + 63) / 64;
    for (int l = 0; l < NLAYERS; l++) {
        aggregate_kernel<<<((size_t)N * 32 + 255) / 256, 256, 0, stream>>>(offsets, csr_src, H, G, N);
        gemm_mfma_kernel<<<gemm_blocks, 256, 0, stream>>>(
            G, wt + (size_t)(2 * l) * D * D, ba + (size_t)l * D, T, nullptr, N);
        gemm_mfma_kernel<<<gemm_blocks, 256, 0, stream>>>(
            T, wt + (size_t)(2 * l + 1) * D * D, bb + (size_t)l * D, G, H, N);
    }

    zero_kernel<<<1, 128, 0, stream>>>(pooled);
    pool_kernel<<<(N + 511) / 512, 256, 0, stream>>>(H, pooled, N);
    final_kernel<<<1, 128, 0, stream>>>(pooled, Wlin, blin, out);
}

// Round 4
// 586.319 us; speedup vs baseline: 10.1251x; 1.5152x over previous
//
#include <hip/hip_runtime.h>

#define D 128
#define NLAYERS 5
#define SCAN_TILE 1024

using short8  = __attribute__((ext_vector_type(8))) short;
using short4v = __attribute__((ext_vector_type(4))) short;
using floatx4 = __attribute__((ext_vector_type(4))) float;

// round-to-nearest-even fp32 -> bf16 (upper-16 bit pattern)
__device__ __forceinline__ unsigned bf16_rne(float x) {
    unsigned u = __float_as_uint(x);
    return (u + 0x7fffu + ((u >> 16) & 1u)) >> 16;
}
__device__ __forceinline__ float bf16_to_f32(short s) {
    return __uint_as_float(((unsigned)(unsigned short)s) << 16);
}

// ---------------- gather: H = bf16(emb[x]) ----------------
__global__ void gather_kernel(const int* __restrict__ x, const float* __restrict__ emb,
                              short* __restrict__ h, int n_nodes) {
    int tid = blockIdx.x * 256 + threadIdx.x;
    int node = tid >> 5;                 // 32 lanes per node
    if (node >= n_nodes) return;
    int lane = tid & 31;
    int s = x[node];
    const float4 v = *reinterpret_cast<const float4*>(emb + (size_t)s * D + lane * 4);
    short4v o;
    o[0] = (short)bf16_rne(v.x); o[1] = (short)bf16_rne(v.y);
    o[2] = (short)bf16_rne(v.z); o[3] = (short)bf16_rne(v.w);
    *reinterpret_cast<short4v*>(h + (size_t)node * D + lane * 4) = o;
}

// ---------------- CSR build ----------------
__global__ void zero_int_kernel(int* __restrict__ p, int n) {
    int i = blockIdx.x * 256 + threadIdx.x;
    if (i < n) p[i] = 0;
}

__global__ void hist_kernel(const int* __restrict__ edst, int* __restrict__ deg, int n_edges) {
    int e = blockIdx.x * 256 + threadIdx.x;
    if (e < n_edges) atomicAdd(&deg[edst[e]], 1);
}

__global__ void scan_sums_kernel(const int* __restrict__ deg, int* __restrict__ bsums, int n) {
    __shared__ int red[256];
    int base = blockIdx.x * SCAN_TILE + threadIdx.x * 4;
    int s = 0;
    #pragma unroll
    for (int j = 0; j < 4; j++) {
        int i = base + j;
        if (i < n) s += deg[i];
    }
    red[threadIdx.x] = s;
    __syncthreads();
    for (int off = 128; off > 0; off >>= 1) {
        if (threadIdx.x < off) red[threadIdx.x] += red[threadIdx.x + off];
        __syncthreads();
    }
    if (threadIdx.x == 0) bsums[blockIdx.x] = red[0];
}

__global__ void scan_bsums_kernel(int* __restrict__ bsums, int nblocks) {
    __shared__ int sdata[256];
    int carry = 0;
    for (int base = 0; base < nblocks; base += 256) {
        int i = base + threadIdx.x;
        int v = (i < nblocks) ? bsums[i] : 0;
        sdata[threadIdx.x] = v;
        __syncthreads();
        for (int off = 1; off < 256; off <<= 1) {
            int t = (threadIdx.x >= off) ? sdata[threadIdx.x - off] : 0;
            __syncthreads();
            sdata[threadIdx.x] += t;
            __syncthreads();
        }
        int incl = sdata[threadIdx.x];
        if (i < nblocks) bsums[i] = carry + incl - v;
        carry += sdata[255];
        __syncthreads();
    }
}

__global__ void scan_final_kernel(const int* __restrict__ deg, const int* __restrict__ bsums,
                                  int* __restrict__ offsets, int* __restrict__ cursor, int n) {
    __shared__ int sdata[256];
    int base = blockIdx.x * SCAN_TILE + threadIdx.x * 4;
    int v[4];
    int s = 0;
    #pragma unroll
    for (int j = 0; j < 4; j++) {
        int i = base + j;
        v[j] = (i < n) ? deg[i] : 0;
        s += v[j];
    }
    sdata[threadIdx.x] = s;
    __syncthreads();
    for (int off = 1; off < 256; off <<= 1) {
        int t = (threadIdx.x >= off) ? sdata[threadIdx.x - off] : 0;
        __syncthreads();
        sdata[threadIdx.x] += t;
        __syncthreads();
    }
    int excl = sdata[threadIdx.x] - s + bsums[blockIdx.x];
    #pragma unroll
    for (int j = 0; j < 4; j++) {
        int i = base + j;
        if (i <= n) offsets[i] = excl;
        if (i < n) cursor[i] = excl;
        excl += v[j];
    }
}

__global__ void fill_kernel(const int* __restrict__ esrc, const int* __restrict__ edst,
                            int* __restrict__ cursor, int* __restrict__ csr_src, int n_edges) {
    int e = blockIdx.x * 256 + threadIdx.x;
    if (e >= n_edges) return;
    int pos = atomicAdd(&cursor[edst[e]], 1);
    csr_src[pos] = esrc[e];
}

// ---------------- aggregation: G[i] = bf16( f32(H[i]) + sum_{j->i} f32(H[j]) ) ----------------
__global__ void aggregate_kernel(const int* __restrict__ offsets, const int* __restrict__ csr_src,
                                 const short* __restrict__ h, short* __restrict__ g, int n_nodes) {
    int tid = blockIdx.x * 256 + threadIdx.x;
    int node = tid >> 4;                 // 16 lanes per node (16B each = 256B row)
    if (node >= n_nodes) return;
    int lane = tid & 15;
    const size_t base = (size_t)node * D + lane * 8;

    float acc[8];
    {
        short8 sv = *reinterpret_cast<const short8*>(h + base);
        #pragma unroll
        for (int j = 0; j < 8; j++) acc[j] = bf16_to_f32(sv[j]);
    }
    int beg = offsets[node];
    int end = offsets[node + 1];
    int e = beg;
    for (; e + 1 < end; e += 2) {
        int s0 = csr_src[e];
        int s1 = csr_src[e + 1];
        short8 v0 = *reinterpret_cast<const short8*>(h + (size_t)s0 * D + lane * 8);
        short8 v1 = *reinterpret_cast<const short8*>(h + (size_t)s1 * D + lane * 8);
        #pragma unroll
        for (int j = 0; j < 8; j++) acc[j] += bf16_to_f32(v0[j]) + bf16_to_f32(v1[j]);
    }
    if (e < end) {
        int s0 = csr_src[e];
        short8 v0 = *reinterpret_cast<const short8*>(h + (size_t)s0 * D + lane * 8);
        #pragma unroll
        for (int j = 0; j < 8; j++) acc[j] += bf16_to_f32(v0[j]);
    }
    short8 o;
    #pragma unroll
    for (int j = 0; j < 8; j++) o[j] = (short)bf16_rne(acc[j]);
    *reinterpret_cast<short8*>(g + base) = o;
}

// ---------------- W prep: wt[mat][n][k] = bf16(W[mat][k][n]) ----------------
__global__ void wsplit_kernel(const float* __restrict__ Wa, const float* __restrict__ Wb,
                              short* __restrict__ wt) {
    int mat = blockIdx.y;
    const float* W = (mat & 1) ? (Wb + (size_t)(mat >> 1) * D * D)
                               : (Wa + (size_t)(mat >> 1) * D * D);
    int idx = blockIdx.x * 256 + threadIdx.x;
    int n = idx >> 7, k = idx & 127;
    wt[(size_t)mat * D * D + idx] = (short)bf16_rne(W[k * D + n]);
}

// ---------------- MFMA GEMM: out = bf16(relu(in @ W + bias)) ----------------
// block: 64 rows x 128 cols, 4 waves of 32x64. K=128 fully staged.
// LDS: zsh 16KB + wsh 32KB = 48KB -> 3 blocks/CU.
// 16B chunks XOR-swizzled: chunk c of row r at (c ^ (r&15)). (0 conflicts, verified R3)
__global__ __launch_bounds__(256, 3) void gemm_mfma_kernel(
        const short* __restrict__ in, const short* __restrict__ wt,
        const float* __restrict__ bias, short* __restrict__ out, int n_rows) {
    __shared__ __align__(16) short zsh[64 * 128];
    __shared__ __align__(16) short wsh[128 * 128];

    const int tid  = threadIdx.x;
    const int row0 = blockIdx.x * 64;

    // stage W (bf16, [n][k]): 2048 chunks of 8 shorts
    #pragma unroll
    for (int i = 0; i < 8; i++) {
        int g = i * 256 + tid;
        int n = g >> 4, c = g & 15;
        short8 v = *reinterpret_cast<const short8*>(wt + n * D + c * 8);
        *reinterpret_cast<short8*>(&wsh[(n * 16 + (c ^ (n & 15))) * 8]) = v;
    }
    // stage z (bf16 rows, direct): 1024 chunks
    #pragma unroll
    for (int i = 0; i < 4; i++) {
        int g = i * 256 + tid;
        int r = g >> 4, c = g & 15;
        int gr = row0 + r;
        short8 v = {0, 0, 0, 0, 0, 0, 0, 0};
        if (gr < n_rows) v = *reinterpret_cast<const short8*>(in + (size_t)gr * D + c * 8);
        *reinterpret_cast<short8*>(&zsh[(r * 16 + (c ^ (r & 15))) * 8]) = v;
    }
    __syncthreads();

    const int lane = tid & 63;
    const int wave = tid >> 6;
    const int wr   = wave & 1;      // 32-row group
    const int wc   = wave >> 1;     // 64-col group
    const int lm   = lane & 15;
    const int quad = lane >> 4;

    floatx4 acc[2][4];
    #pragma unroll
    for (int a = 0; a < 2; a++)
        #pragma unroll
        for (int b = 0; b < 4; b++) acc[a][b] = floatx4{0.f, 0.f, 0.f, 0.f};

    #pragma unroll
    for (int ks = 0; ks < 4; ks++) {
        const int c = ks * 4 + quad;
        short8 av[2], bv[4];
        #pragma unroll
        for (int rs = 0; rs < 2; rs++) {
            int r = wr * 32 + rs * 16 + lm;
            av[rs] = *reinterpret_cast<const short8*>(&zsh[(r * 16 + (c ^ (r & 15))) * 8]);
        }
        #pragma unroll
        for (int cs = 0; cs < 4; cs++) {
            int nn = wc * 64 + cs * 16 + lm;
            bv[cs] = *reinterpret_cast<const short8*>(&wsh[(nn * 16 + (c ^ (nn & 15))) * 8]);
        }
        #pragma unroll
        for (int rs = 0; rs < 2; rs++)
            #pragma unroll
            for (int cs = 0; cs < 4; cs++)
                acc[rs][cs] = __builtin_amdgcn_mfma_f32_16x16x32_bf16(av[rs], bv[cs], acc[rs][cs], 0, 0, 0);
    }

    // epilogue: bias + relu + bf16 store (C layout: row = quad*4+reg, col = lm)
    #pragma unroll
    for (int cs = 0; cs < 4; cs++) {
        int col = wc * 64 + cs * 16 + lm;
        float bv2 = bias[col];
        #pragma unroll
        for (int rs = 0; rs < 2; rs++) {
            #pragma unroll
            for (int reg = 0; reg < 4; reg++) {
                int r = row0 + wr * 32 + rs * 16 + quad * 4 + reg;
                if (r < n_rows) {
                    float v = fmaxf(acc[rs][cs][reg] + bv2, 0.f);
                    out[(size_t)r * D + col] = (short)bf16_rne(v);
                }
            }
        }
    }
}

// ---------------- pooling: pooled[c] = sum_r f32(H[r][c]) ----------------
__global__ void zero_kernel(float* __restrict__ p) { p[threadIdx.x] = 0.f; }

__global__ void pool_kernel(const short* __restrict__ h, float* __restrict__ pooled, int n_rows) {
    const int c8 = threadIdx.x & 15;     // 16B column chunk
    const int rg = threadIdx.x >> 4;     // 16 row-groups
    const int r0 = blockIdx.x * 256;
    const int rend = min(r0 + 256, n_rows);
    float acc[8];
    #pragma unroll
    for (int j = 0; j < 8; j++) acc[j] = 0.f;
    for (int r = r0 + rg; r < rend; r += 16) {
        short8 v = *reinterpret_cast<const short8*>(h + (size_t)r * D + c8 * 8);
        #pragma unroll
        for (int j = 0; j < 8; j++) acc[j] += bf16_to_f32(v[j]);
    }
    __shared__ float red[16][128];
    #pragma unroll
    for (int j = 0; j < 8; j++) red[rg][c8 * 8 + j] = acc[j];
    __syncthreads();
    if (threadIdx.x < 128) {
        float s = 0.f;
        #pragma unroll
        for (int g = 0; g < 16; g++) s += red[g][threadIdx.x];
        atomicAdd(&pooled[threadIdx.x], s);
    }
}

// ---------------- final linear (fp32 exact) ----------------
__global__ void final_kernel(const float* __restrict__ pooled, const float* __restrict__ Wlin,
                             const float* __restrict__ blin, float* __restrict__ out) {
    const int j = threadIdx.x;
    __shared__ float p[D];
    p[j] = pooled[j];
    __syncthreads();
    float s = blin[j];
    #pragma unroll 8
    for (int k = 0; k < D; k++) s += p[k] * Wlin[k * D + j];
    out[j] = s;
}

extern "C" void kernel_launch(void* const* d_in, const int* in_sizes, int n_in,
                              void* d_out, int out_size, void* d_ws, size_t ws_size,
                              hipStream_t stream) {
    const int*   x    = (const int*)d_in[0];
    const int*   ei   = (const int*)d_in[1];
    const float* emb  = (const float*)d_in[2];
    const float* Wa   = (const float*)d_in[3];
    const float* ba   = (const float*)d_in[4];
    const float* Wb   = (const float*)d_in[5];
    const float* bb   = (const float*)d_in[6];
    const float* Wlin = (const float*)d_in[7];
    const float* blin = (const float*)d_in[8];
    float* out = (float*)d_out;

    const int N = in_sizes[0];
    const int E = in_sizes[1] / 2;
    const int* esrc = ei;
    const int* edst = ei + E;

    // workspace layout (activations in bf16)
    short* H = (short*)d_ws;                       // N*D
    short* G = H + (size_t)N * D;                  // N*D
    short* T = G + (size_t)N * D;                  // N*D
    float* pooled = (float*)(T + (size_t)N * D);   // 128
    int* deg     = (int*)(pooled + 128);           // N
    int* offsets = deg + N;                        // N+1
    int* cursor  = offsets + (N + 1);              // N
    int* bsums   = cursor + N;                     // 4096
    int* csr_src = bsums + 4096;                   // E
    uintptr_t wt_addr = ((uintptr_t)(csr_src + E) + 15) & ~(uintptr_t)15;
    short* wt = (short*)wt_addr;                   // [10][128][128] bf16

    const int scan_blocks = (N + 1 + SCAN_TILE - 1) / SCAN_TILE;

    wsplit_kernel<<<dim3(64, 2 * NLAYERS), 256, 0, stream>>>(Wa, Wb, wt);

    zero_int_kernel<<<(N + 255) / 256, 256, 0, stream>>>(deg, N);
    hist_kernel<<<(E + 255) / 256, 256, 0, stream>>>(edst, deg, E);
    scan_sums_kernel<<<scan_blocks, 256, 0, stream>>>(deg, bsums, N);
    scan_bsums_kernel<<<1, 256, 0, stream>>>(bsums, scan_blocks);
    scan_final_kernel<<<scan_blocks, 256, 0, stream>>>(deg, bsums, offsets, cursor, N);
    fill_kernel<<<(E + 255) / 256, 256, 0, stream>>>(esrc, edst, cursor, csr_src, E);

    gather_kernel<<<(N * 32 + 255) / 256, 256, 0, stream>>>(x, emb, H, N);

    const int gemm_blocks = (N + 63) / 64;
    for (int l = 0; l < NLAYERS; l++) {
        aggregate_kernel<<<((size_t)N * 16 + 255) / 256, 256, 0, stream>>>(offsets, csr_src, H, G, N);
        gemm_mfma_kernel<<<gemm_blocks, 256, 0, stream>>>(
            G, wt + (size_t)(2 * l) * D * D, ba + (size_t)l * D, T, N);
        gemm_mfma_kernel<<<gemm_blocks, 256, 0, stream>>>(
            T, wt + (size_t)(2 * l + 1) * D * D, bb + (size_t)l * D, H, N);
    }

    zero_kernel<<<1, 128, 0, stream>>>(pooled);
    pool_kernel<<<(N + 255) / 256, 256, 0, stream>>>(H, pooled, N);
    final_kernel<<<1, 128, 0, stream>>>(pooled, Wlin, blin, out);
}

// Round 5
// 499.649 us; speedup vs baseline: 11.8815x; 1.1735x over previous
//
#include <hip/hip_runtime.h>

#define D 128
#define NLAYERS 5
#define SCAN_TILE 1024

using short8  = __attribute__((ext_vector_type(8))) short;
using short4v = __attribute__((ext_vector_type(4))) short;
using floatx4 = __attribute__((ext_vector_type(4))) float;

// round-to-nearest-even fp32 -> bf16 (upper-16 bit pattern)
__device__ __forceinline__ unsigned bf16_rne(float x) {
    unsigned u = __float_as_uint(x);
    return (u + 0x7fffu + ((u >> 16) & 1u)) >> 16;
}
__device__ __forceinline__ float bf16_to_f32(short s) {
    return __uint_as_float(((unsigned)(unsigned short)s) << 16);
}

// ---------------- gather: H = bf16(emb[x]) ----------------
__global__ void gather_kernel(const int* __restrict__ x, const float* __restrict__ emb,
                              short* __restrict__ h, int n_nodes) {
    int tid = blockIdx.x * 256 + threadIdx.x;
    int node = tid >> 5;
    if (node >= n_nodes) return;
    int lane = tid & 31;
    int s = x[node];
    const float4 v = *reinterpret_cast<const float4*>(emb + (size_t)s * D + lane * 4);
    short4v o;
    o[0] = (short)bf16_rne(v.x); o[1] = (short)bf16_rne(v.y);
    o[2] = (short)bf16_rne(v.z); o[3] = (short)bf16_rne(v.w);
    *reinterpret_cast<short4v*>(h + (size_t)node * D + lane * 4) = o;
}

// ---------------- CSR build ----------------
__global__ void zero_int_kernel(int* __restrict__ p, int n) {
    int i = blockIdx.x * 256 + threadIdx.x;
    if (i < n) p[i] = 0;
}

__global__ void hist_kernel(const int* __restrict__ edst, int* __restrict__ deg, int n_edges) {
    int e = blockIdx.x * 256 + threadIdx.x;
    if (e < n_edges) atomicAdd(&deg[edst[e]], 1);
}

__global__ void scan_sums_kernel(const int* __restrict__ deg, int* __restrict__ bsums, int n) {
    __shared__ int red[256];
    int base = blockIdx.x * SCAN_TILE + threadIdx.x * 4;
    int s = 0;
    #pragma unroll
    for (int j = 0; j < 4; j++) {
        int i = base + j;
        if (i < n) s += deg[i];
    }
    red[threadIdx.x] = s;
    __syncthreads();
    for (int off = 128; off > 0; off >>= 1) {
        if (threadIdx.x < off) red[threadIdx.x] += red[threadIdx.x + off];
        __syncthreads();
    }
    if (threadIdx.x == 0) bsums[blockIdx.x] = red[0];
}

__global__ void scan_bsums_kernel(int* __restrict__ bsums, int nblocks) {
    __shared__ int sdata[256];
    int carry = 0;
    for (int base = 0; base < nblocks; base += 256) {
        int i = base + threadIdx.x;
        int v = (i < nblocks) ? bsums[i] : 0;
        sdata[threadIdx.x] = v;
        __syncthreads();
        for (int off = 1; off < 256; off <<= 1) {
            int t = (threadIdx.x >= off) ? sdata[threadIdx.x - off] : 0;
            __syncthreads();
            sdata[threadIdx.x] += t;
            __syncthreads();
        }
        int incl = sdata[threadIdx.x];
        if (i < nblocks) bsums[i] = carry + incl - v;
        carry += sdata[255];
        __syncthreads();
    }
}

__global__ void scan_final_kernel(const int* __restrict__ deg, const int* __restrict__ bsums,
                                  int* __restrict__ offsets, int* __restrict__ cursor, int n) {
    __shared__ int sdata[256];
    int base = blockIdx.x * SCAN_TILE + threadIdx.x * 4;
    int v[4];
    int s = 0;
    #pragma unroll
    for (int j = 0; j < 4; j++) {
        int i = base + j;
        v[j] = (i < n) ? deg[i] : 0;
        s += v[j];
    }
    sdata[threadIdx.x] = s;
    __syncthreads();
    for (int off = 1; off < 256; off <<= 1) {
        int t = (threadIdx.x >= off) ? sdata[threadIdx.x - off] : 0;
        __syncthreads();
        sdata[threadIdx.x] += t;
        __syncthreads();
    }
    int excl = sdata[threadIdx.x] - s + bsums[blockIdx.x];
    #pragma unroll
    for (int j = 0; j < 4; j++) {
        int i = base + j;
        if (i <= n) offsets[i] = excl;
        if (i < n) cursor[i] = excl;
        excl += v[j];
    }
}

__global__ void fill_kernel(const int* __restrict__ esrc, const int* __restrict__ edst,
                            int* __restrict__ cursor, int* __restrict__ csr_src, int n_edges) {
    int e = blockIdx.x * 256 + threadIdx.x;
    if (e >= n_edges) return;
    int pos = atomicAdd(&cursor[edst[e]], 1);
    csr_src[pos] = esrc[e];
}

// ---------------- W prep: wt[mat][n][k] = bf16(W[mat][k][n]) ----------------
__global__ void wsplit_kernel(const float* __restrict__ Wa, const float* __restrict__ Wb,
                              short* __restrict__ wt) {
    int mat = blockIdx.y;
    const float* W = (mat & 1) ? (Wb + (size_t)(mat >> 1) * D * D)
                               : (Wa + (size_t)(mat >> 1) * D * D);
    int idx = blockIdx.x * 256 + threadIdx.x;
    int n = idx >> 7, k = idx & 127;
    wt[(size_t)mat * D * D + idx] = (short)bf16_rne(W[k * D + n]);
}

// ---------------- fused layer: H_out = relu(relu((H+agg) @ Wa + ba) @ Wb + bb) ----------------
// block: 64 nodes, 512 threads (8 waves). Wave w: rows (w>>1)*16..+15, cols (w&1)*64..+63.
// LDS: zsh 16KB (z tile, reused for t tile) + wa 32KB + wb 32KB = 80KB -> 2 blocks/CU.
// 16B chunks XOR-swizzled: chunk c of row r at (c ^ (r&15)) -> 0 bank conflicts (verified R3/R4).
__global__ __launch_bounds__(512, 4) void layer_kernel(
        const int* __restrict__ offsets, const int* __restrict__ csr_src,
        const short* __restrict__ h_in, const short* __restrict__ wta,
        const short* __restrict__ wtb, const float* __restrict__ ba,
        const float* __restrict__ bb, short* __restrict__ h_out, int n_rows) {
    __shared__ __align__(16) short zsh[64 * 128];     // z tile, then t tile
    __shared__ __align__(16) short wa[128 * 128];
    __shared__ __align__(16) short wb[128 * 128];

    const int tid  = threadIdx.x;
    const int row0 = blockIdx.x * 64;

    // stage Wa/Wb ([n][k] bf16): 2048 chunks each, 4 iters each over 512 threads
    #pragma unroll
    for (int i = 0; i < 4; i++) {
        int g = i * 512 + tid;
        int n = g >> 4, c = g & 15;
        int off = (n * 16 + (c ^ (n & 15))) * 8;
        *reinterpret_cast<short8*>(&wa[off]) =
            *reinterpret_cast<const short8*>(wta + n * D + c * 8);
        *reinterpret_cast<short8*>(&wb[off]) =
            *reinterpret_cast<const short8*>(wtb + n * D + c * 8);
    }

    // aggregation phase: z[r][c*8..] = h[row0+r] + sum_{j->row0+r} h[j]   (fp32 acc, bf16 out)
    #pragma unroll
    for (int i = 0; i < 2; i++) {
        int g = i * 512 + tid;          // 1024 chunks: r = g>>4, c = g&15
        int r = g >> 4, c = g & 15;
        int gr = row0 + r;
        short8 o = {0, 0, 0, 0, 0, 0, 0, 0};
        if (gr < n_rows) {
            float acc[8];
            {
                short8 sv = *reinterpret_cast<const short8*>(h_in + (size_t)gr * D + c * 8);
                #pragma unroll
                for (int j = 0; j < 8; j++) acc[j] = bf16_to_f32(sv[j]);
            }
            int beg = offsets[gr];
            int end = offsets[gr + 1];
            int e = beg;
            for (; e + 1 < end; e += 2) {
                int s0 = csr_src[e];
                int s1 = csr_src[e + 1];
                short8 v0 = *reinterpret_cast<const short8*>(h_in + (size_t)s0 * D + c * 8);
                short8 v1 = *reinterpret_cast<const short8*>(h_in + (size_t)s1 * D + c * 8);
                #pragma unroll
                for (int j = 0; j < 8; j++) acc[j] += bf16_to_f32(v0[j]) + bf16_to_f32(v1[j]);
            }
            if (e < end) {
                int s0 = csr_src[e];
                short8 v0 = *reinterpret_cast<const short8*>(h_in + (size_t)s0 * D + c * 8);
                #pragma unroll
                for (int j = 0; j < 8; j++) acc[j] += bf16_to_f32(v0[j]);
            }
            #pragma unroll
            for (int j = 0; j < 8; j++) o[j] = (short)bf16_rne(acc[j]);
        }
        *reinterpret_cast<short8*>(&zsh[(r * 16 + (c ^ (r & 15))) * 8]) = o;
    }
    __syncthreads();

    const int lane = tid & 63;
    const int wave = tid >> 6;
    const int wr   = wave >> 1;     // 16-row group (0..3)
    const int wc   = wave & 1;      // 64-col group
    const int lm   = lane & 15;
    const int quad = lane >> 4;

    // ---- GEMM1: t = relu(z @ Wa + ba) ----
    floatx4 acc1[4];
    #pragma unroll
    for (int b = 0; b < 4; b++) acc1[b] = floatx4{0.f, 0.f, 0.f, 0.f};
    {
        const int r = wr * 16 + lm;
        #pragma unroll
        for (int ks = 0; ks < 4; ks++) {
            const int c = ks * 4 + quad;
            short8 av = *reinterpret_cast<const short8*>(&zsh[(r * 16 + (c ^ (r & 15))) * 8]);
            #pragma unroll
            for (int cs = 0; cs < 4; cs++) {
                int nn = wc * 64 + cs * 16 + lm;
                short8 bv = *reinterpret_cast<const short8*>(&wa[(nn * 16 + (c ^ (nn & 15))) * 8]);
                acc1[cs] = __builtin_amdgcn_mfma_f32_16x16x32_bf16(av, bv, acc1[cs], 0, 0, 0);
            }
        }
    }
    __syncthreads();   // all zsh reads complete before t overwrites it

    // epilogue1: bias + relu + bf16, write t into zsh (C layout: row=quad*4+reg, col=lm)
    #pragma unroll
    for (int cs = 0; cs < 4; cs++) {
        int col = wc * 64 + cs * 16 + lm;
        float bva = ba[col];
        int cj = col >> 3, ci = col & 7;
        #pragma unroll
        for (int reg = 0; reg < 4; reg++) {
            int r = wr * 16 + quad * 4 + reg;
            float v = fmaxf(acc1[cs][reg] + bva, 0.f);
            zsh[(r * 16 + (cj ^ (r & 15))) * 8 + ci] = (short)bf16_rne(v);
        }
    }
    __syncthreads();

    // ---- GEMM2: h = relu(t @ Wb + bb) ----
    floatx4 acc2[4];
    #pragma unroll
    for (int b = 0; b < 4; b++) acc2[b] = floatx4{0.f, 0.f, 0.f, 0.f};
    {
        const int r = wr * 16 + lm;
        #pragma unroll
        for (int ks = 0; ks < 4; ks++) {
            const int c = ks * 4 + quad;
            short8 av = *reinterpret_cast<const short8*>(&zsh[(r * 16 + (c ^ (r & 15))) * 8]);
            #pragma unroll
            for (int cs = 0; cs < 4; cs++) {
                int nn = wc * 64 + cs * 16 + lm;
                short8 bv = *reinterpret_cast<const short8*>(&wb[(nn * 16 + (c ^ (nn & 15))) * 8]);
                acc2[cs] = __builtin_amdgcn_mfma_f32_16x16x32_bf16(av, bv, acc2[cs], 0, 0, 0);
            }
        }
    }

    // epilogue2: bias + relu + bf16 -> global
    #pragma unroll
    for (int cs = 0; cs < 4; cs++) {
        int col = wc * 64 + cs * 16 + lm;
        float bvb = bb[col];
        #pragma unroll
        for (int reg = 0; reg < 4; reg++) {
            int r = row0 + wr * 16 + quad * 4 + reg;
            if (r < n_rows) {
                float v = fmaxf(acc2[cs][reg] + bvb, 0.f);
                h_out[(size_t)r * D + col] = (short)bf16_rne(v);
            }
        }
    }
}

// ---------------- pooling: pooled[c] = sum_r f32(H[r][c]) ----------------
__global__ void zero_kernel(float* __restrict__ p) { p[threadIdx.x] = 0.f; }

__global__ void pool_kernel(const short* __restrict__ h, float* __restrict__ pooled, int n_rows) {
    const int c8 = threadIdx.x & 15;
    const int rg = threadIdx.x >> 4;
    const int r0 = blockIdx.x * 256;
    const int rend = min(r0 + 256, n_rows);
    float acc[8];
    #pragma unroll
    for (int j = 0; j < 8; j++) acc[j] = 0.f;
    for (int r = r0 + rg; r < rend; r += 16) {
        short8 v = *reinterpret_cast<const short8*>(h + (size_t)r * D + c8 * 8);
        #pragma unroll
        for (int j = 0; j < 8; j++) acc[j] += bf16_to_f32(v[j]);
    }
    __shared__ float red[16][128];
    #pragma unroll
    for (int j = 0; j < 8; j++) red[rg][c8 * 8 + j] = acc[j];
    __syncthreads();
    if (threadIdx.x < 128) {
        float s = 0.f;
        #pragma unroll
        for (int g = 0; g < 16; g++) s += red[g][threadIdx.x];
        atomicAdd(&pooled[threadIdx.x], s);
    }
}

// ---------------- final linear (fp32 exact) ----------------
__global__ void final_kernel(const float* __restrict__ pooled, const float* __restrict__ Wlin,
                             const float* __restrict__ blin, float* __restrict__ out) {
    const int j = threadIdx.x;
    __shared__ float p[D];
    p[j] = pooled[j];
    __syncthreads();
    float s = blin[j];
    #pragma unroll 8
    for (int k = 0; k < D; k++) s += p[k] * Wlin[k * D + j];
    out[j] = s;
}

extern "C" void kernel_launch(void* const* d_in, const int* in_sizes, int n_in,
                              void* d_out, int out_size, void* d_ws, size_t ws_size,
                              hipStream_t stream) {
    const int*   x    = (const int*)d_in[0];
    const int*   ei   = (const int*)d_in[1];
    const float* emb  = (const float*)d_in[2];
    const float* Wa   = (const float*)d_in[3];
    const float* ba   = (const float*)d_in[4];
    const float* Wb   = (const float*)d_in[5];
    const float* bb   = (const float*)d_in[6];
    const float* Wlin = (const float*)d_in[7];
    const float* blin = (const float*)d_in[8];
    float* out = (float*)d_out;

    const int N = in_sizes[0];
    const int E = in_sizes[1] / 2;
    const int* esrc = ei;
    const int* edst = ei + E;

    // workspace layout: H (bf16, double-buffered) | pooled | CSR | wt
    short* H0 = (short*)d_ws;                       // N*D
    short* H1 = H0 + (size_t)N * D;                 // N*D
    float* pooled = (float*)(H1 + (size_t)N * D);   // 128
    int* deg     = (int*)(pooled + 128);            // N
    int* offsets = deg + N;                         // N+1
    int* cursor  = offsets + (N + 1);               // N
    int* bsums   = cursor + N;                      // 4096
    int* csr_src = bsums + 4096;                    // E
    uintptr_t wt_addr = ((uintptr_t)(csr_src + E) + 15) & ~(uintptr_t)15;
    short* wt = (short*)wt_addr;                    // [10][128][128] bf16

    const int scan_blocks = (N + 1 + SCAN_TILE - 1) / SCAN_TILE;

    wsplit_kernel<<<dim3(64, 2 * NLAYERS), 256, 0, stream>>>(Wa, Wb, wt);

    zero_int_kernel<<<(N + 255) / 256, 256, 0, stream>>>(deg, N);
    hist_kernel<<<(E + 255) / 256, 256, 0, stream>>>(edst, deg, E);
    scan_sums_kernel<<<scan_blocks, 256, 0, stream>>>(deg, bsums, N);
    scan_bsums_kernel<<<1, 256, 0, stream>>>(bsums, scan_blocks);
    scan_final_kernel<<<scan_blocks, 256, 0, stream>>>(deg, bsums, offsets, cursor, N);
    fill_kernel<<<(E + 255) / 256, 256, 0, stream>>>(esrc, edst, cursor, csr_src, E);

    gather_kernel<<<(N * 32 + 255) / 256, 256, 0, stream>>>(x, emb, H0, N);

    const int layer_blocks = (N + 63) / 64;
    short* hin = H0; short* hout = H1;
    for (int l = 0; l < NLAYERS; l++) {
        layer_kernel<<<layer_blocks, 512, 0, stream>>>(
            offsets, csr_src, hin,
            wt + (size_t)(2 * l) * D * D, wt + (size_t)(2 * l + 1) * D * D,
            ba + (size_t)l * D, bb + (size_t)l * D, hout, N);
        short* tmp = hin; hin = hout; hout = tmp;
    }

    zero_kernel<<<1, 128, 0, stream>>>(pooled);
    pool_kernel<<<(N + 255) / 256, 256, 0, stream>>>(hin, pooled, N);
    final_kernel<<<1, 128, 0, stream>>>(pooled, Wlin, blin, out);
}